// Round 7
// baseline (72.876 us; speedup 1.0000x reference)
//
#include <hip/hip_runtime.h>

// GNNEmbeds: 3-layer NNConv, scalar edge features.
// W(e) = attr_e*A + B  =>  msg_e = attr_e*(h[src]@A) + (h[src]@B)
// Per layer: U = h@A, V = h@B, R = h@root + bias; h_next = relu(R + gather(msgs)).
// 3 dispatches, gather-into-consumer, no global atomics, no grid sync.
// Round-7: kill serial latency exposures.
//  - GEMM: groups = (mat x k-quarter), 12x32 lanes; all 32 weight float4
//    pre-staged in VGPRs at kernel entry (single exposure, hidden under scan);
//    rows in registers (no redundant weight reads); reduce via staggered LDS
//    atomics into 6KB ob buffer; relu folded into the h-read.
//  - Scan: dst+src+attr loaded unconditionally (one exposure, not a chain).

#define HD    128
#define TR    4        // dst rows per tile -> N=1024 gives 256 blocks (1/CU)
#define CAP   192      // LDS edge-list capacity (mean 32/tile; ~28 sigma)
#define NTHR  512
#define SCR   TR       // scratch row for pad edges

struct Tile {
    float hs[TR + 1][HD];      // gather accumulator (+ scratch row)   2.5KB
    float ob[3][TR][HD];       // GEMM output accumulators             6KB
    int   lrow[CAP + 16];
    int   lsrc[CAP + 16];
    float lattr[CAP + 16];
    int   lcnt;
};

__device__ __forceinline__ void fma4(float4& a, float s, const float4& w) {
    a.x = fmaf(s, w.x, a.x); a.y = fmaf(s, w.y, a.y);
    a.z = fmaf(s, w.z, a.z); a.w = fmaf(s, w.w, a.w);
}

// Scan edges: dst/src/attr read unconditionally (int4/float4), matches appended
// to LDS list, padded to a multiple of 16. First barrier orders prior LDS init.
__device__ __forceinline__ int scan_edges(const int* __restrict__ ei,
                                          const float* __restrict__ attr,
                                          int E, int n0, Tile& g, int t)
{
    if (t == 0) g.lcnt = 0;
    __syncthreads();
    const int nq = E >> 2;
    const int4*   src4 = (const int4*)ei;
    const int4*   dst4 = (const int4*)(ei + E);
    const float4* at4  = (const float4*)attr;
#pragma unroll 4
    for (int i = t; i < nq; i += NTHR) {
        const int4   d = dst4[i];
        const int4   s = src4[i];
        const float4 a = at4[i];
        const unsigned r0 = (unsigned)(d.x - n0);
        const unsigned r1 = (unsigned)(d.y - n0);
        const unsigned r2 = (unsigned)(d.z - n0);
        const unsigned r3 = (unsigned)(d.w - n0);
        if (r0 < TR) { int k = atomicAdd(&g.lcnt, 1); if (k < CAP) { g.lrow[k] = r0; g.lsrc[k] = s.x; g.lattr[k] = a.x; } }
        if (r1 < TR) { int k = atomicAdd(&g.lcnt, 1); if (k < CAP) { g.lrow[k] = r1; g.lsrc[k] = s.y; g.lattr[k] = a.y; } }
        if (r2 < TR) { int k = atomicAdd(&g.lcnt, 1); if (k < CAP) { g.lrow[k] = r2; g.lsrc[k] = s.z; g.lattr[k] = a.z; } }
        if (r3 < TR) { int k = atomicAdd(&g.lcnt, 1); if (k < CAP) { g.lrow[k] = r3; g.lsrc[k] = s.w; g.lattr[k] = a.w; } }
    }
    for (int e = (E & ~3) + t; e < E; e += NTHR) {   // E%4 tail (empty here)
        const unsigned r = (unsigned)(ei[E + e] - n0);
        if (r < TR) { int k = atomicAdd(&g.lcnt, 1); if (k < CAP) { g.lrow[k] = r; g.lsrc[k] = ei[e]; g.lattr[k] = attr[e]; } }
    }
    __syncthreads();
    int cnt = g.lcnt; if (cnt > CAP) cnt = CAP;
    const int pad = (cnt + 15) & ~15;
    if (t < pad - cnt) {
        const int k = cnt + t;
        g.lrow[k] = SCR; g.lsrc[k] = 0; g.lattr[k] = 0.f;
    }
    __syncthreads();
    return pad;
}

// hs[r] += a*U[s] + V[s]; 16 edges in flight x float4 lanes.
__device__ __forceinline__ void gather_uv(const float* __restrict__ U,
                                          const float* __restrict__ V,
                                          Tile& g, int pad, int t)
{
    const int el = t >> 5;
    const int c4 = (t & 31) << 2;
#pragma unroll 2
    for (int base = 0; base < pad; base += 16) {
        const int   i = base + el;
        const int   r = g.lrow[i];
        const int   s = g.lsrc[i];
        const float a = g.lattr[i];
        const float4 u = *(const float4*)(U + (size_t)s * HD + c4);
        const float4 v = *(const float4*)(V + (size_t)s * HD + c4);
        atomicAdd(&g.hs[r][c4 + 0], fmaf(a, u.x, v.x));
        atomicAdd(&g.hs[r][c4 + 1], fmaf(a, u.y, v.y));
        atomicAdd(&g.hs[r][c4 + 2], fmaf(a, u.z, v.z));
        atomicAdd(&g.hs[r][c4 + 3], fmaf(a, u.w, v.w));
    }
    __syncthreads();
}

// Pre-stage one matrix's [k0..k0+31] x 4-col slice into VGPRs.
__device__ __forceinline__ void stage_w(float4 wv[32], const float* __restrict__ Wm,
                                        int k0, int colg)
{
#pragma unroll
    for (int j = 0; j < 32; ++j)
        wv[j] = *(const float4*)(Wm + (size_t)(k0 + j) * HD + colg);
}

// GEMM accumulate: group grp<12 owns (mat m=grp>>2, k-quarter kq=grp&3).
// relu folded into the h-read. Staggered LDS-atomic reduce into g.ob.
template <bool RELU>
__device__ __forceinline__ void gemm_accum(Tile& g, int t, const float4 wv[32])
{
    const int grp = t >> 5;
    if (grp >= 12) return;
    const int kq   = grp & 3;
    const int m    = grp >> 2;
    const int k0   = kq << 5;
    const int colg = (t & 31) << 2;

    float4 acc[TR];
#pragma unroll
    for (int r = 0; r < TR; ++r) acc[r] = make_float4(0.f, 0.f, 0.f, 0.f);

#pragma unroll
    for (int j4 = 0; j4 < 8; ++j4) {
#pragma unroll
        for (int r = 0; r < TR; ++r) {
            float4 h4 = *(const float4*)&g.hs[r][k0 + (j4 << 2)];
            if (RELU) {
                h4.x = fmaxf(h4.x, 0.f); h4.y = fmaxf(h4.y, 0.f);
                h4.z = fmaxf(h4.z, 0.f); h4.w = fmaxf(h4.w, 0.f);
            }
            fma4(acc[r], h4.x, wv[(j4 << 2) + 0]);
            fma4(acc[r], h4.y, wv[(j4 << 2) + 1]);
            fma4(acc[r], h4.z, wv[(j4 << 2) + 2]);
            fma4(acc[r], h4.w, wv[(j4 << 2) + 3]);
        }
    }
    // reduce: 4 kq-groups contend per address; stagger row order by kq
#pragma unroll
    for (int rr = 0; rr < TR; ++rr) {
        const int r = (rr + kq) & (TR - 1);
        atomicAdd(&g.ob[m][r][colg + 0], acc[r].x);
        atomicAdd(&g.ob[m][r][colg + 1], acc[r].y);
        atomicAdd(&g.ob[m][r][colg + 2], acc[r].z);
        atomicAdd(&g.ob[m][r][colg + 3], acc[r].w);
    }
}

// Store ob -> U,V,R (R += bias). 384 float4, coalesced.
__device__ __forceinline__ void store_out(Tile& g, int n0, int t,
    const float* __restrict__ bias,
    float* __restrict__ U, float* __restrict__ V, float* __restrict__ R)
{
    if (t < 384) {
        const int m = t >> 7;             // 0..2
        const int rc = t & 127;
        const int r = rc >> 5, c = (rc & 31) << 2;
        float4 v = *(const float4*)&g.ob[m][r][c];
        float* O;
        if (m == 2) {
            const float4 bv = *(const float4*)(bias + c);
            v.x += bv.x; v.y += bv.y; v.z += bv.z; v.w += bv.w;
            O = R;
        } else O = (m == 0) ? U : V;
        *(float4*)(O + (size_t)(n0 + r) * HD + c) = v;
    }
}

__device__ __forceinline__ void zero_ob(Tile& g, int t) {
    if (t < 384) ((float4*)&g.ob[0][0][0])[t] = make_float4(0.f, 0.f, 0.f, 0.f);
}

// ---- G2: layer-1 gather (msgs on the fly from x, in_c=2) + layer-2 GEMMs ----
__global__ __launch_bounds__(NTHR, 2) void g2k(
    const float* __restrict__ x, const int* __restrict__ ei,
    const float* __restrict__ attr,
    const float* __restrict__ lw1, const float* __restrict__ lb1,
    const float* __restrict__ root1, const float* __restrict__ bias1,
    const float* __restrict__ lw2, const float* __restrict__ lb2,
    const float* __restrict__ root2, const float* __restrict__ bias2,
    float* __restrict__ U2, float* __restrict__ V2, float* __restrict__ R2,
    int E)
{
    __shared__ Tile g;
    const int t = threadIdx.x;
    const int n0 = blockIdx.x * TR;
    const int grp = t >> 5;
    const int colg = (t & 31) << 2;

    // pre-stage layer-2 weights (held in VGPRs through scan/gather)
    float4 wv[32];
    if (grp < 12) {
        const float* Wm = (grp >> 2) == 0 ? lw2 : (grp >> 2) == 1 ? lb2 : root2;
        stage_w(wv, Wm, (grp & 3) << 5, colg);
    }
    // pre-stage layer-1 message weight columns
    const float4 A0 = *(const float4*)(lw1 + colg);
    const float4 A1 = *(const float4*)(lw1 + HD + colg);
    const float4 B0 = *(const float4*)(lb1 + colg);
    const float4 B1 = *(const float4*)(lb1 + HD + colg);

    // hs = x@root1 + bias1  (TR*HD == NTHR)
    {
        const int r = t >> 7, c = t & 127;
        const float x0 = x[(n0 + r) * 2 + 0], x1 = x[(n0 + r) * 2 + 1];
        g.hs[r][c] = fmaf(x0, root1[c], fmaf(x1, root1[HD + c], bias1[c]));
    }
    zero_ob(g, t);

    const int pad = scan_edges(ei, attr, E, n0, g, t);

    // gather layer-1 messages: msg[c] = a*(x@A1)[c] + (x@B1)[c]
    const int el = t >> 5;
#pragma unroll 2
    for (int base = 0; base < pad; base += 16) {
        const int   i = base + el;
        const int   r = g.lrow[i];
        const int   s = g.lsrc[i];
        const float a = g.lattr[i];
        const float2 xv = *(const float2*)(x + (size_t)s * 2);
        atomicAdd(&g.hs[r][colg + 0], fmaf(a, fmaf(xv.x, A0.x, xv.y * A1.x), fmaf(xv.x, B0.x, xv.y * B1.x)));
        atomicAdd(&g.hs[r][colg + 1], fmaf(a, fmaf(xv.x, A0.y, xv.y * A1.y), fmaf(xv.x, B0.y, xv.y * B1.y)));
        atomicAdd(&g.hs[r][colg + 2], fmaf(a, fmaf(xv.x, A0.z, xv.y * A1.z), fmaf(xv.x, B0.z, xv.y * B1.z)));
        atomicAdd(&g.hs[r][colg + 3], fmaf(a, fmaf(xv.x, A0.w, xv.y * A1.w), fmaf(xv.x, B0.w, xv.y * B1.w)));
    }
    __syncthreads();

    gemm_accum<true>(g, t, wv);
    __syncthreads();
    store_out(g, n0, t, bias2, U2, V2, R2);
}

// ---- G3: layer-2 gather + layer-3 GEMMs ----
__global__ __launch_bounds__(NTHR, 2) void g3k(
    const int* __restrict__ ei, const float* __restrict__ attr,
    const float* __restrict__ U2, const float* __restrict__ V2,
    const float* __restrict__ R2,
    const float* __restrict__ lw3, const float* __restrict__ lb3,
    const float* __restrict__ root3, const float* __restrict__ bias3,
    float* __restrict__ U3, float* __restrict__ V3, float* __restrict__ R3,
    int E)
{
    __shared__ Tile g;
    const int t = threadIdx.x;
    const int n0 = blockIdx.x * TR;
    const int grp = t >> 5;
    const int colg = (t & 31) << 2;

    float4 wv[32];
    if (grp < 12) {
        const float* Wm = (grp >> 2) == 0 ? lw3 : (grp >> 2) == 1 ? lb3 : root3;
        stage_w(wv, Wm, (grp & 3) << 5, colg);
    }

    if (t < TR * HD / 4)
        ((float4*)&g.hs[0][0])[t] = ((const float4*)(R2 + (size_t)n0 * HD))[t];
    zero_ob(g, t);

    const int pad = scan_edges(ei, attr, E, n0, g, t);
    gather_uv(U2, V2, g, pad, t);
    gemm_accum<true>(g, t, wv);
    __syncthreads();
    store_out(g, n0, t, bias3, U3, V3, R3);
}

// ---- G4: layer-3 gather -> out (no relu, plain float4 stores) ----
__global__ __launch_bounds__(NTHR, 2) void g4k(
    const int* __restrict__ ei, const float* __restrict__ attr,
    const float* __restrict__ U3, const float* __restrict__ V3,
    const float* __restrict__ R3, float* __restrict__ out, int E)
{
    __shared__ Tile g;
    const int t = threadIdx.x;
    const int n0 = blockIdx.x * TR;

    if (t < TR * HD / 4)
        ((float4*)&g.hs[0][0])[t] = ((const float4*)(R3 + (size_t)n0 * HD))[t];

    const int pad = scan_edges(ei, attr, E, n0, g, t);
    gather_uv(U3, V3, g, pad, t);

    if (t < TR * HD / 4)
        ((float4*)(out + (size_t)n0 * HD))[t] = ((const float4*)&g.hs[0][0])[t];
}

extern "C" void kernel_launch(void* const* d_in, const int* in_sizes, int n_in,
                              void* d_out, int out_size, void* d_ws, size_t ws_size,
                              hipStream_t stream) {
    const float* x     = (const float*)d_in[0];
    const int*   ei    = (const int*)  d_in[1];
    const float* attr  = (const float*)d_in[2];
    const float* lw1   = (const float*)d_in[3];
    const float* lb1   = (const float*)d_in[4];
    const float* root1 = (const float*)d_in[5];
    const float* bias1 = (const float*)d_in[6];
    const float* lw2   = (const float*)d_in[7];
    const float* lb2   = (const float*)d_in[8];
    const float* root2 = (const float*)d_in[9];
    const float* bias2 = (const float*)d_in[10];
    const float* lw3   = (const float*)d_in[11];
    const float* lb3   = (const float*)d_in[12];
    const float* root3 = (const float*)d_in[13];
    const float* bias3 = (const float*)d_in[14];

    const int N = in_sizes[0] / 2;   // x: [N,2]
    const int E = in_sizes[1] / 2;   // edge_index: [2,E]

    float* out = (float*)d_out;
    float* ws  = (float*)d_ws;
    float* U2 = ws + 0 * (size_t)N * HD;
    float* V2 = ws + 1 * (size_t)N * HD;
    float* R2 = ws + 2 * (size_t)N * HD;
    float* U3 = ws + 3 * (size_t)N * HD;
    float* V3 = ws + 4 * (size_t)N * HD;
    float* R3 = ws + 5 * (size_t)N * HD;

    const int ntiles = N / TR;   // 256 blocks, ~1 per CU
    g2k<<<ntiles, NTHR, 0, stream>>>(x, ei, attr, lw1, lb1, root1, bias1,
                                     lw2, lb2, root2, bias2, U2, V2, R2, E);
    g3k<<<ntiles, NTHR, 0, stream>>>(ei, attr, U2, V2, R2,
                                     lw3, lb3, root3, bias3, U3, V3, R3, E);
    g4k<<<ntiles, NTHR, 0, stream>>>(ei, attr, U3, V3, R3, out, E);
}

// Round 8
// 67.680 us; speedup vs baseline: 1.0768x; 1.0768x over previous
//
#include <hip/hip_runtime.h>

// GNNEmbeds: 3-layer NNConv, scalar edge features.
// W(e) = attr_e*A + B  =>  msg_e = attr_e*(h[src]@A) + (h[src]@B)
// Per layer: U = h@A, V = h@B, R = h@root + bias; h_next = relu(R + gather(msgs)).
// 3 dispatches, gather-into-consumer, no global atomics, no grid sync.
// Round-8 (from R6 baseline, R7 regression reverted):
//  - GEMM: 12 groups (mat x k-quarter), each owns all TR rows -> weights pulled
//    ONCE per block (192KB, was 768KB); weight batches loaded JIT (8 k-rows =
//    32 transient VGPRs, no spill; NO launch_bounds min-wave cap); staggered
//    LDS-atomic reduce into ob; relu folded into the LDS h-read.
//  - Scan once in g2k, persist padded edge lists to ws; g3k/g4k load their
//    list in one coalesced exposure (no rescan, 2 fewer barriers).

#define HD    128
#define TR    4          // dst rows per tile -> N=1024 gives 256 blocks (1/CU)
#define CAP   192        // LDS edge-list capacity (mean 32/tile)
#define CAPP  (CAP + 16) // padded stride for persisted lists
#define NTHR  512
#define SCR   TR         // scratch row for pad edges

struct Tile {
    float hs[TR + 1][HD];      // gather accumulator (+ scratch row)
    float ob[3][TR][HD];       // GEMM output accumulators
    int   lrow[CAPP];
    int   lsrc[CAPP];
    float lattr[CAPP];
    int   lcnt;
};

__device__ __forceinline__ void fma4(float4& a, float s, const float4& w) {
    a.x = fmaf(s, w.x, a.x); a.y = fmaf(s, w.y, a.y);
    a.z = fmaf(s, w.z, a.z); a.w = fmaf(s, w.w, a.w);
}

// Scan edges (g2k only): dst/src/attr read unconditionally, matches appended
// to LDS list, padded to multiple of 16. First barrier orders prior LDS init.
__device__ __forceinline__ int scan_edges(const int* __restrict__ ei,
                                          const float* __restrict__ attr,
                                          int E, int n0, Tile& g, int t)
{
    if (t == 0) g.lcnt = 0;
    __syncthreads();
    const int nq = E >> 2;
    const int4*   src4 = (const int4*)ei;
    const int4*   dst4 = (const int4*)(ei + E);
    const float4* at4  = (const float4*)attr;
#pragma unroll 4
    for (int i = t; i < nq; i += NTHR) {
        const int4   d = dst4[i];
        const int4   s = src4[i];
        const float4 a = at4[i];
        const unsigned r0 = (unsigned)(d.x - n0);
        const unsigned r1 = (unsigned)(d.y - n0);
        const unsigned r2 = (unsigned)(d.z - n0);
        const unsigned r3 = (unsigned)(d.w - n0);
        if (r0 < TR) { int k = atomicAdd(&g.lcnt, 1); if (k < CAP) { g.lrow[k] = r0; g.lsrc[k] = s.x; g.lattr[k] = a.x; } }
        if (r1 < TR) { int k = atomicAdd(&g.lcnt, 1); if (k < CAP) { g.lrow[k] = r1; g.lsrc[k] = s.y; g.lattr[k] = a.y; } }
        if (r2 < TR) { int k = atomicAdd(&g.lcnt, 1); if (k < CAP) { g.lrow[k] = r2; g.lsrc[k] = s.z; g.lattr[k] = a.z; } }
        if (r3 < TR) { int k = atomicAdd(&g.lcnt, 1); if (k < CAP) { g.lrow[k] = r3; g.lsrc[k] = s.w; g.lattr[k] = a.w; } }
    }
    for (int e = (E & ~3) + t; e < E; e += NTHR) {   // E%4 tail (empty here)
        const unsigned r = (unsigned)(ei[E + e] - n0);
        if (r < TR) { int k = atomicAdd(&g.lcnt, 1); if (k < CAP) { g.lrow[k] = r; g.lsrc[k] = ei[e]; g.lattr[k] = attr[e]; } }
    }
    __syncthreads();
    int cnt = g.lcnt; if (cnt > CAP) cnt = CAP;
    const int pad = (cnt + 15) & ~15;
    if (t < pad - cnt) {
        const int k = cnt + t;
        g.lrow[k] = SCR; g.lsrc[k] = 0; g.lattr[k] = 0.f;
    }
    __syncthreads();
    return pad;
}

// hs[r] += a*U[s] + V[s]; 16 edges in flight x float4 lanes.
__device__ __forceinline__ void gather_uv(const float* __restrict__ U,
                                          const float* __restrict__ V,
                                          Tile& g, int pad, int t)
{
    const int el = t >> 5;
    const int c4 = (t & 31) << 2;
#pragma unroll 2
    for (int base = 0; base < pad; base += 16) {
        const int   i = base + el;
        const int   r = g.lrow[i];
        const int   s = g.lsrc[i];
        const float a = g.lattr[i];
        const float4 u = *(const float4*)(U + (size_t)s * HD + c4);
        const float4 v = *(const float4*)(V + (size_t)s * HD + c4);
        atomicAdd(&g.hs[r][c4 + 0], fmaf(a, u.x, v.x));
        atomicAdd(&g.hs[r][c4 + 1], fmaf(a, u.y, v.y));
        atomicAdd(&g.hs[r][c4 + 2], fmaf(a, u.z, v.z));
        atomicAdd(&g.hs[r][c4 + 3], fmaf(a, u.w, v.w));
    }
    __syncthreads();
}

// GEMM accumulate: 12 groups of 32 lanes = (mat m, k-quarter kq). Each group
// covers all TR rows for its 32 k-rows -> each weight element read once/block.
// Weights loaded JIT in 8-k-row batches (32 transient VGPRs). relu on h-read.
template <bool RELU>
__device__ __forceinline__ void gemm_accum(Tile& g, int t,
    const float* __restrict__ Wa, const float* __restrict__ Wb,
    const float* __restrict__ Wr)
{
    const int grp = t >> 5;
    if (grp >= 12) return;
    const int m    = grp >> 2;
    const int kq   = grp & 3;
    const int k0   = kq << 5;
    const int colg = (t & 31) << 2;
    const float* Wm = (m == 0) ? Wa : (m == 1) ? Wb : Wr;

    float4 acc[TR];
#pragma unroll
    for (int r = 0; r < TR; ++r) acc[r] = make_float4(0.f, 0.f, 0.f, 0.f);

#pragma unroll 1
    for (int kb = 0; kb < 32; kb += 8) {
        float4 wv[8];
#pragma unroll
        for (int j = 0; j < 8; ++j)
            wv[j] = *(const float4*)(Wm + (size_t)(k0 + kb + j) * HD + colg);
#pragma unroll
        for (int r = 0; r < TR; ++r) {
            float4 h0 = *(const float4*)&g.hs[r][k0 + kb];
            float4 h1 = *(const float4*)&g.hs[r][k0 + kb + 4];
            if (RELU) {
                h0.x = fmaxf(h0.x, 0.f); h0.y = fmaxf(h0.y, 0.f);
                h0.z = fmaxf(h0.z, 0.f); h0.w = fmaxf(h0.w, 0.f);
                h1.x = fmaxf(h1.x, 0.f); h1.y = fmaxf(h1.y, 0.f);
                h1.z = fmaxf(h1.z, 0.f); h1.w = fmaxf(h1.w, 0.f);
            }
            fma4(acc[r], h0.x, wv[0]); fma4(acc[r], h0.y, wv[1]);
            fma4(acc[r], h0.z, wv[2]); fma4(acc[r], h0.w, wv[3]);
            fma4(acc[r], h1.x, wv[4]); fma4(acc[r], h1.y, wv[5]);
            fma4(acc[r], h1.z, wv[6]); fma4(acc[r], h1.w, wv[7]);
        }
    }
    // 4 kq-groups reduce per (m,row,col): stagger row order by kq
#pragma unroll
    for (int rr = 0; rr < TR; ++rr) {
        const int r = (rr + kq) & (TR - 1);
        atomicAdd(&g.ob[m][r][colg + 0], acc[r].x);
        atomicAdd(&g.ob[m][r][colg + 1], acc[r].y);
        atomicAdd(&g.ob[m][r][colg + 2], acc[r].z);
        atomicAdd(&g.ob[m][r][colg + 3], acc[r].w);
    }
}

// Store ob -> U,V,R (R += bias). 384 float4, coalesced.
__device__ __forceinline__ void store_out(Tile& g, int n0, int t,
    const float* __restrict__ bias,
    float* __restrict__ U, float* __restrict__ V, float* __restrict__ R)
{
    if (t < 384) {
        const int m = t >> 7;
        const int rc = t & 127;
        const int r = rc >> 5, c = (rc & 31) << 2;
        float4 v = *(const float4*)&g.ob[m][r][c];
        float* O;
        if (m == 2) {
            const float4 bv = *(const float4*)(bias + c);
            v.x += bv.x; v.y += bv.y; v.z += bv.z; v.w += bv.w;
            O = R;
        } else O = (m == 0) ? U : V;
        *(float4*)(O + (size_t)(n0 + r) * HD + c) = v;
    }
}

__device__ __forceinline__ void zero_ob(Tile& g, int t) {
    if (t < 384) ((float4*)&g.ob[0][0][0])[t] = make_float4(0.f, 0.f, 0.f, 0.f);
}

// Load persisted edge list for this tile into LDS (one coalesced exposure).
__device__ __forceinline__ int load_list(const int* __restrict__ gecnt,
                                         const int* __restrict__ gerow,
                                         const int* __restrict__ gesrc,
                                         const float* __restrict__ geattr,
                                         int tile, Tile& g, int t)
{
    const int pad = gecnt[tile];           // broadcast load
    const int base = tile * CAPP;
    if (t < pad) {
        g.lrow[t]  = gerow[base + t];
        g.lsrc[t]  = gesrc[base + t];
        g.lattr[t] = geattr[base + t];
    }
    __syncthreads();
    return pad;
}

// ---- G2: layer-1 gather (msgs on the fly from x, in_c=2) + layer-2 GEMMs ----
__global__ __launch_bounds__(NTHR) void g2k(
    const float* __restrict__ x, const int* __restrict__ ei,
    const float* __restrict__ attr,
    const float* __restrict__ lw1, const float* __restrict__ lb1,
    const float* __restrict__ root1, const float* __restrict__ bias1,
    const float* __restrict__ lw2, const float* __restrict__ lb2,
    const float* __restrict__ root2, const float* __restrict__ bias2,
    float* __restrict__ U2, float* __restrict__ V2, float* __restrict__ R2,
    int* __restrict__ gecnt, int* __restrict__ gerow,
    int* __restrict__ gesrc, float* __restrict__ geattr,
    int E)
{
    __shared__ Tile g;
    const int t = threadIdx.x;
    const int n0 = blockIdx.x * TR;
    const int colg = (t & 31) << 2;

    // hs = x@root1 + bias1  (TR*HD == NTHR)
    {
        const int r = t >> 7, c = t & 127;
        const float x0 = x[(n0 + r) * 2 + 0], x1 = x[(n0 + r) * 2 + 1];
        g.hs[r][c] = fmaf(x0, root1[c], fmaf(x1, root1[HD + c], bias1[c]));
    }
    zero_ob(g, t);

    const int pad = scan_edges(ei, attr, E, n0, g, t);

    // persist padded list for g3k/g4k
    {
        const int base = blockIdx.x * CAPP;
        if (t < pad) {
            gerow[base + t]  = g.lrow[t];
            gesrc[base + t]  = g.lsrc[t];
            geattr[base + t] = g.lattr[t];
        }
        if (t == 0) gecnt[blockIdx.x] = pad;
    }

    // gather layer-1 messages: msg[c] = a*(x@A1)[c] + (x@B1)[c]
    const float4 A0 = *(const float4*)(lw1 + colg);
    const float4 A1 = *(const float4*)(lw1 + HD + colg);
    const float4 B0 = *(const float4*)(lb1 + colg);
    const float4 B1 = *(const float4*)(lb1 + HD + colg);
    const int el = t >> 5;
#pragma unroll 2
    for (int base = 0; base < pad; base += 16) {
        const int   i = base + el;
        const int   r = g.lrow[i];
        const int   s = g.lsrc[i];
        const float a = g.lattr[i];
        const float2 xv = *(const float2*)(x + (size_t)s * 2);
        atomicAdd(&g.hs[r][colg + 0], fmaf(a, fmaf(xv.x, A0.x, xv.y * A1.x), fmaf(xv.x, B0.x, xv.y * B1.x)));
        atomicAdd(&g.hs[r][colg + 1], fmaf(a, fmaf(xv.x, A0.y, xv.y * A1.y), fmaf(xv.x, B0.y, xv.y * B1.y)));
        atomicAdd(&g.hs[r][colg + 2], fmaf(a, fmaf(xv.x, A0.z, xv.y * A1.z), fmaf(xv.x, B0.z, xv.y * B1.z)));
        atomicAdd(&g.hs[r][colg + 3], fmaf(a, fmaf(xv.x, A0.w, xv.y * A1.w), fmaf(xv.x, B0.w, xv.y * B1.w)));
    }
    __syncthreads();

    gemm_accum<true>(g, t, lw2, lb2, root2);
    __syncthreads();
    store_out(g, n0, t, bias2, U2, V2, R2);
}

// ---- G3: layer-2 gather (list from ws) + layer-3 GEMMs ----
__global__ __launch_bounds__(NTHR) void g3k(
    const float* __restrict__ U2, const float* __restrict__ V2,
    const float* __restrict__ R2,
    const float* __restrict__ lw3, const float* __restrict__ lb3,
    const float* __restrict__ root3, const float* __restrict__ bias3,
    float* __restrict__ U3, float* __restrict__ V3, float* __restrict__ R3,
    const int* __restrict__ gecnt, const int* __restrict__ gerow,
    const int* __restrict__ gesrc, const float* __restrict__ geattr)
{
    __shared__ Tile g;
    const int t = threadIdx.x;
    const int n0 = blockIdx.x * TR;

    if (t < TR * HD / 4)
        ((float4*)&g.hs[0][0])[t] = ((const float4*)(R2 + (size_t)n0 * HD))[t];
    zero_ob(g, t);

    const int pad = load_list(gecnt, gerow, gesrc, geattr, blockIdx.x, g, t);
    gather_uv(U2, V2, g, pad, t);
    gemm_accum<true>(g, t, lw3, lb3, root3);
    __syncthreads();
    store_out(g, n0, t, bias3, U3, V3, R3);
}

// ---- G4: layer-3 gather (list from ws) -> out (no relu, plain stores) ----
__global__ __launch_bounds__(NTHR) void g4k(
    const float* __restrict__ U3, const float* __restrict__ V3,
    const float* __restrict__ R3, float* __restrict__ out,
    const int* __restrict__ gecnt, const int* __restrict__ gerow,
    const int* __restrict__ gesrc, const float* __restrict__ geattr)
{
    __shared__ Tile g;
    const int t = threadIdx.x;
    const int n0 = blockIdx.x * TR;

    if (t < TR * HD / 4)
        ((float4*)&g.hs[0][0])[t] = ((const float4*)(R3 + (size_t)n0 * HD))[t];

    const int pad = load_list(gecnt, gerow, gesrc, geattr, blockIdx.x, g, t);
    gather_uv(U3, V3, g, pad, t);

    if (t < TR * HD / 4)
        ((float4*)(out + (size_t)n0 * HD))[t] = ((const float4*)&g.hs[0][0])[t];
}

extern "C" void kernel_launch(void* const* d_in, const int* in_sizes, int n_in,
                              void* d_out, int out_size, void* d_ws, size_t ws_size,
                              hipStream_t stream) {
    const float* x     = (const float*)d_in[0];
    const int*   ei    = (const int*)  d_in[1];
    const float* attr  = (const float*)d_in[2];
    const float* lw1   = (const float*)d_in[3];
    const float* lb1   = (const float*)d_in[4];
    const float* root1 = (const float*)d_in[5];
    const float* bias1 = (const float*)d_in[6];
    const float* lw2   = (const float*)d_in[7];
    const float* lb2   = (const float*)d_in[8];
    const float* root2 = (const float*)d_in[9];
    const float* bias2 = (const float*)d_in[10];
    const float* lw3   = (const float*)d_in[11];
    const float* lb3   = (const float*)d_in[12];
    const float* root3 = (const float*)d_in[13];
    const float* bias3 = (const float*)d_in[14];

    const int N = in_sizes[0] / 2;   // x: [N,2]
    const int E = in_sizes[1] / 2;   // edge_index: [2,E]
    const int ntiles = N / TR;       // 256 blocks, ~1 per CU

    float* out = (float*)d_out;
    float* ws  = (float*)d_ws;
    float* U2 = ws + 0 * (size_t)N * HD;
    float* V2 = ws + 1 * (size_t)N * HD;
    float* R2 = ws + 2 * (size_t)N * HD;
    float* U3 = ws + 3 * (size_t)N * HD;
    float* V3 = ws + 4 * (size_t)N * HD;
    float* R3 = ws + 5 * (size_t)N * HD;
    int*   gecnt  = (int*)(ws + 6 * (size_t)N * HD);
    int*   gerow  = gecnt + ntiles;
    int*   gesrc  = gerow + (size_t)ntiles * CAPP;
    float* geattr = (float*)(gesrc + (size_t)ntiles * CAPP);

    g2k<<<ntiles, NTHR, 0, stream>>>(x, ei, attr, lw1, lb1, root1, bias1,
                                     lw2, lb2, root2, bias2, U2, V2, R2,
                                     gecnt, gerow, gesrc, geattr, E);
    g3k<<<ntiles, NTHR, 0, stream>>>(U2, V2, R2, lw3, lb3, root3, bias3,
                                     U3, V3, R3, gecnt, gerow, gesrc, geattr);
    g4k<<<ntiles, NTHR, 0, stream>>>(U3, V3, R3, out,
                                     gecnt, gerow, gesrc, geattr);
}